// Round 3
// baseline (60.303 us; speedup 1.0000x reference)
//
#include <hip/hip_runtime.h>

// Comb filter: y[n] = x[n-D] + f*y[n-D], y[n]=0 for n<D.
// N = 16777216, D = 4096 -> 4096 independent chains of K = 4096 steps each.
// Chain c, step k: a_k = x[k*D + c]; y_0 = 0; y_{k+1} = f*y_k + a_k;
// output[k*D + c] = y_k.
//
// Two kernels (no grid sync):
//   K1 carry: per (segment s, chain-quad c4) C_s = sum_j f^(SEGLEN-1-j) a_j
//             reads x (64 MiB), writes g_carry (2 MiB).
//   K2 scan+emit: each block re-derives its segment-start state
//             Y_s = Horner scan of C_0..C_{s-1} with factor f^SEGLEN
//             (<=127 independent L2/L3-resident row loads + short fma chain),
//             then replays the exact recurrence, re-reading x (L3-hot from K1)
//             and writing y (64 MiB).
// Identical arithmetic order to the verified round-1 kernel -> absmax 0.

#define N_TOTAL 16777216
#define D       4096
#define K_STEPS (N_TOTAL / D)    // 4096
#define SEGS    128              // segments per chain
#define SEGLEN  (K_STEPS / SEGS) // 32 steps per segment
#define D4      (D / 4)          // 1024 float4 per k-row

// 2 MiB scratch in a device global (fully rewritten every call).
__device__ float g_carry[SEGS * D];

__global__ __launch_bounds__(256)
void comb_carry(const float* __restrict__ x, const float* __restrict__ fptr) {
    const float f = fptr[0];
    const int c4 = (blockIdx.x & 3) * 256 + threadIdx.x;  // 0..1023
    const int s  = blockIdx.x >> 2;                       // 0..127
    const float4* __restrict__ xp = (const float4*)x;
    const int base = s * SEGLEN * D4 + c4;

    float4 acc = make_float4(0.f, 0.f, 0.f, 0.f);
    #pragma unroll 8
    for (int k = 0; k < SEGLEN; ++k) {
        float4 a = xp[base + k * D4];
        acc.x = f * acc.x + a.x;
        acc.y = f * acc.y + a.y;
        acc.z = f * acc.z + a.z;
        acc.w = f * acc.w + a.w;
    }
    ((float4*)g_carry)[s * D4 + c4] = acc;
}

__global__ __launch_bounds__(256)
void comb_scan_emit(const float* __restrict__ x, const float* __restrict__ fptr,
                    float* __restrict__ out) {
    const float f = fptr[0];
    const int c4 = (blockIdx.x & 3) * 256 + threadIdx.x;  // 0..1023
    const int s  = blockIdx.x >> 2;                       // 0..127
    const float4* __restrict__ xp = (const float4*)x;
    float4* __restrict__ op = (float4*)out;

    // fL = f^SEGLEN via 5 squarings (SEGLEN = 32)
    float fL = f * f;          // f^2
    fL = fL * fL;              // f^4
    fL = fL * fL;              // f^8
    fL = fL * fL;              // f^16
    fL = fL * fL;              // f^32

    // Segment-start state: Horner scan over earlier carries (L2/L3 resident).
    // Same accumulation order as the round-1 scan kernel -> bit-identical.
    const float4* __restrict__ cp = (const float4*)g_carry;
    float4 Y = make_float4(0.f, 0.f, 0.f, 0.f);
    for (int t = 0; t < s; ++t) {
        float4 C = cp[t * D4 + c4];
        Y.x = fL * Y.x + C.x;
        Y.y = fL * Y.y + C.y;
        Y.z = fL * Y.z + C.z;
        Y.w = fL * Y.w + C.w;
    }

    // Replay exact recurrence from Y, write y.
    const int base = s * SEGLEN * D4 + c4;
    float4 y = Y;
    #pragma unroll 8
    for (int k = 0; k < SEGLEN; ++k) {
        const int idx = base + k * D4;
        op[idx] = y;
        float4 a = xp[idx];
        y.x = f * y.x + a.x;
        y.y = f * y.y + a.y;
        y.z = f * y.z + a.z;
        y.w = f * y.w + a.w;
    }
}

extern "C" void kernel_launch(void* const* d_in, const int* in_sizes, int n_in,
                              void* d_out, int out_size, void* d_ws, size_t ws_size,
                              hipStream_t stream) {
    const float* x = (const float*)d_in[0];
    const float* f = (const float*)d_in[1];
    float* out = (float*)d_out;
    (void)in_sizes; (void)n_in; (void)d_ws; (void)ws_size; (void)out_size;

    dim3 blk(256);
    dim3 grid(SEGS * 4);   // 512 blocks

    comb_carry<<<grid, blk, 0, stream>>>(x, f);
    comb_scan_emit<<<grid, blk, 0, stream>>>(x, f, out);
}

// Round 4
// 36.024 us; speedup vs baseline: 1.6740x; 1.6740x over previous
//
#include <hip/hip_runtime.h>

// Comb filter: y[n] = x[n-D] + f*y[n-D], y[n]=0 for n<D.
// N = 16777216, D = 4096 -> 4096 independent chains of K = 4096 steps each.
// Chain c, step k: a_k = x[k*D + c]; y_0 = 0; y_{k+1} = f*y_k + a_k;
// output[k*D + c] = y_k.
//
// Two kernels:
//   K1 carry: per (segment s, chain-quad c4) C_s = sum_j f^(SEGLEN-1-j) a_j.
//   K2 scan+emit: block for segment s computes
//         Y_s = sum_{t<s} fL^(s-1-t) C_t   (fL = f^SEGLEN)
//     as an ORDER-FREE weighted sum with batched independent loads and 4
//     accumulators (no serial load->fma chain), then replays the exact
//     recurrence from Y_s using x preloaded into registers, writes y.
// R3 lesson: the serial Horner scan was latency-bound (~225cy L2 load-use
// x 127 deps on the tail block). Weighted-sum form makes it L2-BW-bound.

#define N_TOTAL 16777216
#define D       4096
#define K_STEPS (N_TOTAL / D)    // 4096
#define SEGS    128              // segments per chain
#define SEGLEN  (K_STEPS / SEGS) // 32 steps per segment
#define D4      (D / 4)          // 1024 float4 per k-row

// 2 MiB scratch in a device global (fully rewritten every call).
__device__ float g_carry[SEGS * D];

__global__ __launch_bounds__(256)
void comb_carry(const float* __restrict__ x, const float* __restrict__ fptr) {
    const float f = fptr[0];
    const int c4 = (blockIdx.x & 3) * 256 + threadIdx.x;  // 0..1023
    const int s  = blockIdx.x >> 2;                       // 0..127
    const float4* __restrict__ xp = (const float4*)x;
    const int base = s * SEGLEN * D4 + c4;

    float4 acc = make_float4(0.f, 0.f, 0.f, 0.f);
    #pragma unroll 8
    for (int k = 0; k < SEGLEN; ++k) {
        float4 a = xp[base + k * D4];
        acc.x = f * acc.x + a.x;
        acc.y = f * acc.y + a.y;
        acc.z = f * acc.z + a.z;
        acc.w = f * acc.w + a.w;
    }
    ((float4*)g_carry)[s * D4 + c4] = acc;
}

__global__ __launch_bounds__(256)
void comb_scan_emit(const float* __restrict__ x, const float* __restrict__ fptr,
                    float* __restrict__ out) {
    const float f = fptr[0];
    const int c4 = (blockIdx.x & 3) * 256 + threadIdx.x;  // 0..1023
    const int s  = blockIdx.x >> 2;                       // 0..127
    const float4* __restrict__ xp = (const float4*)x;
    float4* __restrict__ op = (float4*)out;
    const int base = s * SEGLEN * D4 + c4;

    // ---- Preload this segment's x into registers (32 independent loads,
    //      issued first so their latency hides under the scan below) ----
    float4 xa[SEGLEN];
    #pragma unroll
    for (int k = 0; k < SEGLEN; ++k) xa[k] = xp[base + k * D4];

    // fL = f^SEGLEN via 5 squarings (SEGLEN = 32)
    float fL = f * f;
    fL = fL * fL;
    fL = fL * fL;
    fL = fL * fL;
    fL = fL * fL;

    // ---- Segment-start state as an order-free weighted sum:
    //      Y_s = sum_{t=0}^{s-1} fL^(s-1-t) * C_t
    //      (iterate t downward; weight starts at 1, *= fL each step).
    //      4 independent accumulators + batched loads -> no serial chain. ----
    const float4* __restrict__ cp = (const float4*)g_carry;
    float4 Y0 = make_float4(0.f, 0.f, 0.f, 0.f);
    float4 Y1 = Y0, Y2 = Y0, Y3 = Y0;
    float w = 1.f;
    int t = s - 1;
    const float fL2 = fL * fL;
    const float fL4 = fL2 * fL2;
    #pragma unroll 4
    for (; t >= 3; t -= 4) {
        float4 C0 = cp[(t    ) * D4 + c4];
        float4 C1 = cp[(t - 1) * D4 + c4];
        float4 C2 = cp[(t - 2) * D4 + c4];
        float4 C3 = cp[(t - 3) * D4 + c4];
        const float w0 = w, w1 = w * fL, w2 = w * fL2, w3 = w1 * fL2;
        Y0.x += w0 * C0.x; Y0.y += w0 * C0.y; Y0.z += w0 * C0.z; Y0.w += w0 * C0.w;
        Y1.x += w1 * C1.x; Y1.y += w1 * C1.y; Y1.z += w1 * C1.z; Y1.w += w1 * C1.w;
        Y2.x += w2 * C2.x; Y2.y += w2 * C2.y; Y2.z += w2 * C2.z; Y2.w += w2 * C2.w;
        Y3.x += w3 * C3.x; Y3.y += w3 * C3.y; Y3.z += w3 * C3.z; Y3.w += w3 * C3.w;
        w = w * fL4;
    }
    for (; t >= 0; --t) {
        float4 C = cp[t * D4 + c4];
        Y0.x += w * C.x; Y0.y += w * C.y; Y0.z += w * C.z; Y0.w += w * C.w;
        w *= fL;
    }
    float4 y;
    y.x = (Y0.x + Y1.x) + (Y2.x + Y3.x);
    y.y = (Y0.y + Y1.y) + (Y2.y + Y3.y);
    y.z = (Y0.z + Y1.z) + (Y2.z + Y3.z);
    y.w = (Y0.w + Y1.w) + (Y2.w + Y3.w);

    // ---- Replay exact recurrence from Y_s, write y ----
    #pragma unroll
    for (int k = 0; k < SEGLEN; ++k) {
        op[base + k * D4] = y;
        y.x = f * y.x + xa[k].x;
        y.y = f * y.y + xa[k].y;
        y.z = f * y.z + xa[k].z;
        y.w = f * y.w + xa[k].w;
    }
}

extern "C" void kernel_launch(void* const* d_in, const int* in_sizes, int n_in,
                              void* d_out, int out_size, void* d_ws, size_t ws_size,
                              hipStream_t stream) {
    const float* x = (const float*)d_in[0];
    const float* f = (const float*)d_in[1];
    float* out = (float*)d_out;
    (void)in_sizes; (void)n_in; (void)d_ws; (void)ws_size; (void)out_size;

    dim3 blk(256);
    dim3 grid(SEGS * 4);   // 512 blocks

    comb_carry<<<grid, blk, 0, stream>>>(x, f);
    comb_scan_emit<<<grid, blk, 0, stream>>>(x, f, out);
}